// Round 2
// baseline (6811.436 us; speedup 1.0000x reference)
//
#include <hip/hip_runtime.h>
#include <math.h>

#define BATCH 2048
#define L 168
#define NBK 14
#define BSZ 12
#define C0 588
#define C1 512
#define C2 384
#define C3 256
#define NTOT (BATCH*L)

// ws layout in floats:
//  [0..1]   sum, sumsq
//  [16..]   mask (16*144 = 2304)
//  then w0T (588*512), w1T (512*384), w2T (384*256)
#define WS_MASK 16
#define WS_W0T (WS_MASK + 16*144)
#define WS_W1T (WS_W0T + C0*C1)
#define WS_W2T (WS_W1T + C1*C2)

__global__ __launch_bounds__(256) void stats_kernel(const float* __restrict__ x, float* ws) {
    __shared__ float s_sum[256], s_sq[256];
    int tid = threadIdx.x;
    int idx = blockIdx.x * 256 + tid;
    float sum = 0.f, sq = 0.f;
    const float4* x4 = (const float4*)x;
    for (int i = idx; i < NTOT / 4; i += gridDim.x * 256) {
        float4 v = x4[i];
        sum += v.x + v.y + v.z + v.w;
        sq  += v.x*v.x + v.y*v.y + v.z*v.z + v.w*v.w;
    }
    s_sum[tid] = sum; s_sq[tid] = sq;
    __syncthreads();
    for (int s = 128; s > 0; s >>= 1) {
        if (tid < s) { s_sum[tid] += s_sum[tid+s]; s_sq[tid] += s_sq[tid+s]; }
        __syncthreads();
    }
    if (tid == 0) { atomicAdd(&ws[0], s_sum[0]); atomicAdd(&ws[1], s_sq[0]); }
}

__global__ __launch_bounds__(256) void prep_kernel(const float* __restrict__ w0,
                                                   const float* __restrict__ w1,
                                                   const float* __restrict__ w2,
                                                   float* __restrict__ ws) {
    int idx = blockIdx.x * 256 + threadIdx.x;
    int stride = gridDim.x * 256;
    float* w0T = ws + WS_W0T;
    float* w1T = ws + WS_W1T;
    float* w2T = ws + WS_W2T;
    for (int i = idx; i < C0*C1; i += stride) { int c = i >> 9, o = i & 511; w0T[i] = w0[o*C0 + c]; }
    for (int i = idx; i < C1*C2; i += stride) { int c = i / C2, o = i - c*C2; w1T[i] = w1[o*C1 + c]; }
    for (int i = idx; i < C2*C3; i += stride) { int c = i >> 8, o = i & 255; w2T[i] = w2[o*C2 + c]; }
}

__global__ __launch_bounds__(256) void mask_kernel(const float* __restrict__ wm, float* __restrict__ ws) {
    __shared__ float sv[256];
    int g = blockIdx.x, t = threadIdx.x;
    float v = (t < 144) ? wm[g*144 + t] : -INFINITY;
    sv[t] = v;
    __syncthreads();
    for (int s = 128; s > 0; s >>= 1) { if (t < s) sv[t] = fmaxf(sv[t], sv[t+s]); __syncthreads(); }
    float mx = sv[0];
    __syncthreads();
    float e = (t < 144) ? expf(v - mx) : 0.f;
    sv[t] = e;
    __syncthreads();
    for (int s = 128; s > 0; s >>= 1) { if (t < s) sv[t] += sv[t+s]; __syncthreads(); }
    if (t < 144) ws[WS_MASK + g*144 + t] = e / sv[0];
}

// One block per batch element. 256 threads.
// LDS: xn[168] | fT[588][12] (reused as h1T[384][12]) | h0T[512][12]
__global__ __launch_bounds__(256) void fused_kernel(const float* __restrict__ x,
                                                    const float* __restrict__ b0,
                                                    const float* __restrict__ b1,
                                                    const float* __restrict__ b2,
                                                    const float* __restrict__ ws,
                                                    float* __restrict__ out) {
    __shared__ float smem[168 + C0*BSZ + C1*BSZ];
    float* xn  = smem;                       // 168
    float* fT  = smem + 168;                 // 588*12, reused as h1T (384*12)
    float* h0T = smem + 168 + C0*BSZ;        // 512*12

    const float* maskv = ws + WS_MASK;
    const float* w0T = ws + WS_W0T;
    const float* w1T = ws + WS_W1T;
    const float* w2T = ws + WS_W2T;

    int b = blockIdx.x, t = threadIdx.x;

    float sum = ws[0], sq = ws[1];
    float mean = sum / (float)NTOT;
    float var  = (sq - sum * mean) / (float)(NTOT - 1);
    float istd = 1.0f / sqrtf(var);
    if (t < L) xn[t] = (x[b*L + t] - mean) * istd;

    float rb0a = b0[t];
    float rb0b = b0[t + 256];
    float rb1a = b1[t];
    bool  two  = (t < 128);
    float rb1b = two ? b1[t + 256] : 0.f;
    float rb2  = b2[t];
    int g = t >> 4;
    float pooled = 0.f;
    __syncthreads();

    const float4* fT4  = (const float4*)fT;
    const float4* h0T4 = (const float4*)h0T;

    for (int cc = 0; cc < 12; ++cc) {            // cc == h (row of positions)
        // ---- phase A: features for 12 positions (w = m), channels c=(n1*14+n2)*3+f
        for (int k = 0; k < 10; ++k) {
            int pi = t + 256*k;                  // pi = pair*12 + m, 196*12 = 2352 total
            if (pi < 2352) {
                int pr = pi / 12;
                int m  = pi - pr*12;
                int n1 = pr / 14, n2 = pr - n1*14;
                float xi = xn[n1*12 + cc];       // 'c' term: x[b, p]
                float xj = xn[n2*12 + m];        // 'a' term: x[b, q]
                float DI = xj - xi;
                float s  = xi + xj + 1e-5f;
                float r  = __builtin_amdgcn_rcpf(s);
                fT[(pr*3 + 0)*BSZ + m] = DI;
                fT[(pr*3 + 1)*BSZ + m] = DI * r;
                fT[(pr*3 + 2)*BSZ + m] = xj * r;
            }
        }
        __syncthreads();

        // ---- phase B: layer0 (588 -> 512), thread owns o = t and o = t+256
        {
            float a0[12], a1[12];
            #pragma unroll
            for (int m = 0; m < 12; ++m) { a0[m] = 0.f; a1[m] = 0.f; }
            const float* wp = w0T + t;
            #pragma unroll 2
            for (int c = 0; c < C0; ++c) {
                float wv0 = wp[c*C1];
                float wv1 = wp[c*C1 + 256];
                float fm[12];
                *(float4*)&fm[0] = fT4[c*3 + 0];
                *(float4*)&fm[4] = fT4[c*3 + 1];
                *(float4*)&fm[8] = fT4[c*3 + 2];
                #pragma unroll
                for (int m = 0; m < 12; ++m) {
                    a0[m] = fmaf(fm[m], wv0, a0[m]);
                    a1[m] = fmaf(fm[m], wv1, a1[m]);
                }
            }
            #pragma unroll
            for (int m = 0; m < 12; ++m) {
                h0T[t*BSZ + m]        = fmaxf(a0[m] + rb0a, 0.f);
                h0T[(t+256)*BSZ + m]  = fmaxf(a1[m] + rb0b, 0.f);
            }
        }
        __syncthreads();

        // ---- phase C: layer1 (512 -> 384); o = t for all, o = t+256 for t<128
        {
            float a0[12], a1[12];
            #pragma unroll
            for (int m = 0; m < 12; ++m) { a0[m] = 0.f; a1[m] = 0.f; }
            const float* wp = w1T + t;
            #pragma unroll 2
            for (int c = 0; c < C1; ++c) {
                float fm[12];
                *(float4*)&fm[0] = h0T4[c*3 + 0];
                *(float4*)&fm[4] = h0T4[c*3 + 1];
                *(float4*)&fm[8] = h0T4[c*3 + 2];
                float wv0 = wp[c*C2];
                #pragma unroll
                for (int m = 0; m < 12; ++m) a0[m] = fmaf(fm[m], wv0, a0[m]);
                if (two) {
                    float wv1 = wp[c*C2 + 256];
                    #pragma unroll
                    for (int m = 0; m < 12; ++m) a1[m] = fmaf(fm[m], wv1, a1[m]);
                }
            }
            // h1T overlays fT (fT no longer needed)
            #pragma unroll
            for (int m = 0; m < 12; ++m) fT[t*BSZ + m] = fmaxf(a0[m] + rb1a, 0.f);
            if (two) {
                #pragma unroll
                for (int m = 0; m < 12; ++m) fT[(t+256)*BSZ + m] = fmaxf(a1[m] + rb1b, 0.f);
            }
        }
        __syncthreads();

        // ---- phase D: layer2 (384 -> 256) + pooling; o = t
        {
            float a0[12];
            #pragma unroll
            for (int m = 0; m < 12; ++m) a0[m] = 0.f;
            const float* wp = w2T + t;
            #pragma unroll 2
            for (int c = 0; c < C2; ++c) {
                float fm[12];
                *(float4*)&fm[0] = fT4[c*3 + 0];
                *(float4*)&fm[4] = fT4[c*3 + 1];
                *(float4*)&fm[8] = fT4[c*3 + 2];
                float wv = wp[c*C3];
                #pragma unroll
                for (int m = 0; m < 12; ++m) a0[m] = fmaf(fm[m], wv, a0[m]);
            }
            float mv[12];
            *(float4*)&mv[0] = *(const float4*)(maskv + g*144 + cc*12);
            *(float4*)&mv[4] = *(const float4*)(maskv + g*144 + cc*12 + 4);
            *(float4*)&mv[8] = *(const float4*)(maskv + g*144 + cc*12 + 8);
            #pragma unroll
            for (int m = 0; m < 12; ++m) pooled += fmaxf(a0[m] + rb2, 0.f) * mv[m];
        }
        __syncthreads();
    }

    out[b*256 + t] = fmaxf(pooled, 0.f);
}

extern "C" void kernel_launch(void* const* d_in, const int* in_sizes, int n_in,
                              void* d_out, int out_size, void* d_ws, size_t ws_size,
                              hipStream_t stream) {
    const float* x  = (const float*)d_in[0];
    const float* w0 = (const float*)d_in[1];
    const float* b0 = (const float*)d_in[2];
    const float* w1 = (const float*)d_in[3];
    const float* b1 = (const float*)d_in[4];
    const float* w2 = (const float*)d_in[5];
    const float* b2 = (const float*)d_in[6];
    const float* wm = (const float*)d_in[7];
    float* out = (float*)d_out;
    float* ws  = (float*)d_ws;

    hipMemsetAsync(d_ws, 0, 8, stream);
    stats_kernel<<<256, 256, 0, stream>>>(x, ws);
    prep_kernel<<<512, 256, 0, stream>>>(w0, w1, w2, ws);
    mask_kernel<<<16, 256, 0, stream>>>(wm, ws);
    fused_kernel<<<2048, 256, 0, stream>>>(x, b0, b1, b2, ws, out);
}

// Round 3
// 481.312 us; speedup vs baseline: 14.1518x; 14.1518x over previous
//
#include <hip/hip_runtime.h>
#include <math.h>

#define BATCH 2048
#define L 168
#define NTOT (BATCH*L)

typedef unsigned short ushort_t;
typedef __attribute__((ext_vector_type(8))) short bhalf8;
typedef __attribute__((ext_vector_type(4))) float f32x4;

// ---- ws byte layout ----
// [0..8)        sum,sumsq (float)
// [64..9280)    mask 16*144 float  (float idx 16..2320)
#define WS_MASK_F 16
#define OFF_W0P 9280            // 19*512*32 ushort = 622592
#define OFF_W1P (OFF_W0P + 19*512*32*2)   // 631872
#define OFF_W2P (OFF_W1P + 16*384*32*2)   // 1025088
// end 1221696

// ---- LDS layout (bytes) ----
#define H0_STRIDE 520   // ushort elems; 1040B: bank-offset 4 -> conflict-free
#define H1_STRIDE 392   // 784B: bank-offset 4 -> conflict-free
#define FA_STRIDE 40    // 80B: bank-offset 20 -> conflict-free, 16B aligned
#define OFF_FA 149760   // 144*520*2
#define OFF_XN 161280   // OFF_FA + 144*40*2
#define OFF_LUT 161984  // OFF_XN + 176*4
#define LDS_TOTAL 162392

__device__ __forceinline__ ushort_t f2bf(float v) {
    union { float f; unsigned int u; } q; q.f = v;
    unsigned int u = q.u;
    u += 0x7FFFu + ((u >> 16) & 1u);
    return (ushort_t)(u >> 16);
}

__global__ __launch_bounds__(256) void stats_kernel(const float* __restrict__ x, float* ws) {
    __shared__ float s_sum[256], s_sq[256];
    int tid = threadIdx.x;
    int idx = blockIdx.x * 256 + tid;
    float sum = 0.f, sq = 0.f;
    const float4* x4 = (const float4*)x;
    for (int i = idx; i < NTOT / 4; i += gridDim.x * 256) {
        float4 v = x4[i];
        sum += v.x + v.y + v.z + v.w;
        sq  += v.x*v.x + v.y*v.y + v.z*v.z + v.w*v.w;
    }
    s_sum[tid] = sum; s_sq[tid] = sq;
    __syncthreads();
    for (int s = 128; s > 0; s >>= 1) {
        if (tid < s) { s_sum[tid] += s_sum[tid+s]; s_sq[tid] += s_sq[tid+s]; }
        __syncthreads();
    }
    if (tid == 0) { atomicAdd(&ws[0], s_sum[0]); atomicAdd(&ws[1], s_sq[0]); }
}

__global__ __launch_bounds__(256) void mask_kernel(const float* __restrict__ wm, float* __restrict__ ws) {
    __shared__ float sv[256];
    int g = blockIdx.x, t = threadIdx.x;
    float v = (t < 144) ? wm[g*144 + t] : -INFINITY;
    sv[t] = v;
    __syncthreads();
    for (int s = 128; s > 0; s >>= 1) { if (t < s) sv[t] = fmaxf(sv[t], sv[t+s]); __syncthreads(); }
    float mx = sv[0];
    __syncthreads();
    float e = (t < 144) ? expf(v - mx) : 0.f;
    sv[t] = e;
    __syncthreads();
    for (int s = 128; s > 0; s >>= 1) { if (t < s) sv[t] += sv[t+s]; __syncthreads(); }
    if (t < 144) ws[WS_MASK_F + g*144 + t] = e / sv[0];
}

// Pack weights to bf16, K-tile-major [kt][o][32] so a wave's B-fragment load is 1KB contiguous.
__global__ __launch_bounds__(256) void prep_bf16(const float* __restrict__ w0, const float* __restrict__ w1,
                                                 const float* __restrict__ w2,
                                                 ushort_t* __restrict__ w0p, ushort_t* __restrict__ w1p,
                                                 ushort_t* __restrict__ w2p) {
    int idx = blockIdx.x * 256 + threadIdx.x;
    int stride = gridDim.x * 256;
    for (int i = idx; i < 19*16384; i += stride) {       // 512*32 = 16384
        int kk = i & 31, o = (i >> 5) & 511, kt = i >> 14;
        int c = kt*32 + kk;
        float v = (c < 588) ? w0[o*588 + c] : 0.f;
        w0p[i] = f2bf(v);
    }
    for (int i = idx; i < 16*12288; i += stride) {       // 384*32 = 12288
        int kk = i & 31; int t = i >> 5; int o = t % 384; int kt = t / 384;
        w1p[i] = f2bf(w1[o*512 + kt*32 + kk]);
    }
    for (int i = idx; i < 12*8192; i += stride) {        // 256*32 = 8192
        int kk = i & 31, o = (i >> 5) & 255, kt = i >> 13;
        w2p[i] = f2bf(w2[o*384 + kt*32 + kk]);
    }
}

// One block per batch. 512 threads = 8 waves. Full M=144 (9 MFMA row-tiles).
__global__ __launch_bounds__(512, 2) void fused_mfma(
    const float* __restrict__ x, const float* __restrict__ b0,
    const float* __restrict__ b1, const float* __restrict__ b2,
    const float* __restrict__ wsf,
    const ushort_t* __restrict__ w0p, const ushort_t* __restrict__ w1p,
    const ushort_t* __restrict__ w2p, float* __restrict__ out)
{
    __shared__ __align__(16) char smem[LDS_TOTAL];
    ushort_t* h0s  = (ushort_t*)smem;              // [144][520] bf16; later h1 [144][392]
    ushort_t* fA   = (ushort_t*)(smem + OFF_FA);   // [144][40] bf16 feature K-tile
    float*    xns  = (float*)(smem + OFF_XN);      // [168]
    ushort_t* lutP = (ushort_t*)(smem + OFF_LUT);  // [204] (n1*12)<<8 | n2*12

    const int tid  = threadIdx.x;
    const int b    = blockIdx.x;
    const int lane = tid & 63;
    const int w    = tid >> 6;
    const int col  = lane & 15;
    const int r4   = lane >> 4;

    // ---- global stats + xn + LUT ----
    {
        float sum = wsf[0], sq = wsf[1];
        float mean = sum / (float)NTOT;
        float var  = (sq - sum * mean) / (float)(NTOT - 1);
        float istd = 1.0f / sqrtf(var);
        if (tid < 168) xns[tid] = (x[b*L + tid] - mean) * istd;
        if (tid < 204) {
            int n1 = tid / 14, n2 = tid - n1*14;
            lutP[tid] = (ushort_t)(((n1*12) << 8) | (n2*12));
        }
    }
    __syncthreads();

    // ---- feature generation for K-tile kt: fA[r][kk], c = kt*32+kk ----
    const int kk    = tid & 31;
    const int rbase = tid >> 5;   // 0..15
    auto gen = [&](int kt) {
        int c = kt*32 + kk;
        int pr = c / 3;
        int f  = c - pr*3;
        ushort_t lu = lutP[pr];
        int i1 = lu >> 8, i2 = lu & 255;
        bool valid = (c < 588);
        #pragma unroll
        for (int j = 0; j < 9; ++j) {
            int r = rbase + 16*j;          // 0..143
            int h = (r * 171) >> 11;       // r/12 for r<144
            int wv = r - h*12;
            float xi = xns[i1 + h];
            float xj = xns[i2 + wv];
            float DI = xj - xi;
            float s  = xi + xj + 1e-5f;
            float rc = __builtin_amdgcn_rcpf(s);
            float v  = (f == 0) ? DI : ((f == 1) ? DI*rc : xj*rc);
            v = valid ? v : 0.f;
            fA[r*FA_STRIDE + kk] = f2bf(v);
        }
    };

    // ================= Layer 0: 588(608)->512, 19 K-tiles =================
    {
        const int NT0 = w * 4;   // 4 n-tiles per wave
        f32x4 acc[9][4];
        #pragma unroll
        for (int m = 0; m < 9; ++m)
            #pragma unroll
            for (int nt = 0; nt < 4; ++nt) acc[m][nt] = (f32x4){0.f,0.f,0.f,0.f};

        bhalf8 BA[4], BB[4];
        #define LOADB0(dst, ktv) { _Pragma("unroll") \
            for (int nt = 0; nt < 4; ++nt) \
                dst[nt] = *(const bhalf8*)(w0p + (ktv)*16384 + ((NT0+nt)*16+col)*32 + r4*8); }
        #define PHASE0(B) { _Pragma("unroll") \
            for (int m = 0; m < 9; ++m) { \
                bhalf8 a = *(const bhalf8*)(fA + (m*16+col)*FA_STRIDE + r4*8); \
                _Pragma("unroll") \
                for (int nt = 0; nt < 4; ++nt) \
                    acc[m][nt] = __builtin_amdgcn_mfma_f32_16x16x32_bf16(a, B[nt], acc[m][nt], 0, 0, 0); } }

        LOADB0(BA, 0);
        for (int ktb = 0; ktb < 9; ++ktb) {
            int kt = 2*ktb;
            gen(kt);
            __syncthreads();
            LOADB0(BB, kt+1);
            PHASE0(BA);
            __syncthreads();
            gen(kt+1);
            __syncthreads();
            if (kt+2 < 19) LOADB0(BA, kt+2);
            PHASE0(BB);
            __syncthreads();
        }
        gen(18);
        __syncthreads();
        PHASE0(BA);
        // epilogue: bias+relu -> bf16 -> h0s
        float bb[4];
        #pragma unroll
        for (int nt = 0; nt < 4; ++nt) bb[nt] = b0[(NT0+nt)*16 + col];
        __syncthreads();   // all fA reads done (not strictly needed; cheap)
        #pragma unroll
        for (int m = 0; m < 9; ++m)
            #pragma unroll
            for (int nt = 0; nt < 4; ++nt)
                #pragma unroll
                for (int q = 0; q < 4; ++q) {
                    float v = fmaxf(acc[m][nt][q] + bb[nt], 0.f);
                    h0s[(m*16 + r4*4 + q)*H0_STRIDE + (NT0+nt)*16 + col] = f2bf(v);
                }
    }
    __syncthreads();

    // ================= Layer 1: 512->384, 16 K-tiles, no barriers in loop =================
    f32x4 acc1[9][3];
    {
        const int NT1 = w * 3;
        #pragma unroll
        for (int m = 0; m < 9; ++m)
            #pragma unroll
            for (int nt = 0; nt < 3; ++nt) acc1[m][nt] = (f32x4){0.f,0.f,0.f,0.f};

        bhalf8 BA[3], BB[3];
        #define LOADB1(dst, ktv) { _Pragma("unroll") \
            for (int nt = 0; nt < 3; ++nt) \
                dst[nt] = *(const bhalf8*)(w1p + (ktv)*12288 + ((NT1+nt)*16+col)*32 + r4*8); }
        #define PHASE1(B, ktv) { _Pragma("unroll") \
            for (int m = 0; m < 9; ++m) { \
                bhalf8 a = *(const bhalf8*)(h0s + (m*16+col)*H0_STRIDE + (ktv)*32 + r4*8); \
                _Pragma("unroll") \
                for (int nt = 0; nt < 3; ++nt) \
                    acc1[m][nt] = __builtin_amdgcn_mfma_f32_16x16x32_bf16(a, B[nt], acc1[m][nt], 0, 0, 0); } }

        LOADB1(BA, 0);
        for (int ktb = 0; ktb < 8; ++ktb) {
            int kt = 2*ktb;
            LOADB1(BB, kt+1);
            PHASE1(BA, kt);
            if (kt+2 < 16) LOADB1(BA, kt+2);
            PHASE1(BB, kt+1);
        }
        __syncthreads();   // all h0 reads done before h1 overwrite
        const int NT1b = NT1;
        float bb[3];
        #pragma unroll
        for (int nt = 0; nt < 3; ++nt) bb[nt] = b1[(NT1b+nt)*16 + col];
        #pragma unroll
        for (int m = 0; m < 9; ++m)
            #pragma unroll
            for (int nt = 0; nt < 3; ++nt)
                #pragma unroll
                for (int q = 0; q < 4; ++q) {
                    float v = fmaxf(acc1[m][nt][q] + bb[nt], 0.f);
                    h0s[(m*16 + r4*4 + q)*H1_STRIDE + (NT1b+nt)*16 + col] = f2bf(v);
                }
    }
    // stage mask into fA region (free now): 16*144 floats
    {
        float* maskS = (float*)(smem + OFF_FA);
        const float* maskG = wsf + WS_MASK_F;
        for (int i = tid; i < 2304; i += 512) maskS[i] = maskG[i];
    }
    __syncthreads();   // h1 + mask ready

    // ================= Layer 2: 384->256, 12 K-tiles + pooled epilogue =================
    {
        const int NT2 = w * 2;
        f32x4 acc[9][2];
        #pragma unroll
        for (int m = 0; m < 9; ++m)
            #pragma unroll
            for (int nt = 0; nt < 2; ++nt) acc[m][nt] = (f32x4){0.f,0.f,0.f,0.f};

        bhalf8 BA[2], BB[2];
        #define LOADB2(dst, ktv) { _Pragma("unroll") \
            for (int nt = 0; nt < 2; ++nt) \
                dst[nt] = *(const bhalf8*)(w2p + (ktv)*8192 + ((NT2+nt)*16+col)*32 + r4*8); }
        #define PHASE2(B, ktv) { _Pragma("unroll") \
            for (int m = 0; m < 9; ++m) { \
                bhalf8 a = *(const bhalf8*)(h0s + (m*16+col)*H1_STRIDE + (ktv)*32 + r4*8); \
                _Pragma("unroll") \
                for (int nt = 0; nt < 2; ++nt) \
                    acc[m][nt] = __builtin_amdgcn_mfma_f32_16x16x32_bf16(a, B[nt], acc[m][nt], 0, 0, 0); } }

        LOADB2(BA, 0);
        for (int ktb = 0; ktb < 6; ++ktb) {
            int kt = 2*ktb;
            LOADB2(BB, kt+1);
            PHASE2(BA, kt);
            if (kt+2 < 12) LOADB2(BA, kt+2);
            PHASE2(BB, kt+1);
        }
        const float* maskS = (const float*)(smem + OFF_FA);
        float bb[2];
        #pragma unroll
        for (int nt = 0; nt < 2; ++nt) bb[nt] = b2[(NT2+nt)*16 + col];
        float pooled[2] = {0.f, 0.f};
        #pragma unroll
        for (int nt = 0; nt < 2; ++nt) {
            int g = NT2 + nt;
            #pragma unroll
            for (int m = 0; m < 9; ++m)
                #pragma unroll
                for (int q = 0; q < 4; ++q) {
                    int p = m*16 + r4*4 + q;
                    float v = fmaxf(acc[m][nt][q] + bb[nt], 0.f);
                    pooled[nt] += maskS[g*144 + p] * v;
                }
        }
        #pragma unroll
        for (int nt = 0; nt < 2; ++nt) {
            pooled[nt] += __shfl_xor(pooled[nt], 16);
            pooled[nt] += __shfl_xor(pooled[nt], 32);
            if (r4 == 0) out[b*256 + (NT2+nt)*16 + col] = fmaxf(pooled[nt], 0.f);
        }
    }
}

extern "C" void kernel_launch(void* const* d_in, const int* in_sizes, int n_in,
                              void* d_out, int out_size, void* d_ws, size_t ws_size,
                              hipStream_t stream) {
    const float* x  = (const float*)d_in[0];
    const float* w0 = (const float*)d_in[1];
    const float* b0 = (const float*)d_in[2];
    const float* w1 = (const float*)d_in[3];
    const float* b1 = (const float*)d_in[4];
    const float* w2 = (const float*)d_in[5];
    const float* b2 = (const float*)d_in[6];
    const float* wm = (const float*)d_in[7];
    float* out = (float*)d_out;
    float* wsf = (float*)d_ws;
    ushort_t* w0p = (ushort_t*)((char*)d_ws + OFF_W0P);
    ushort_t* w1p = (ushort_t*)((char*)d_ws + OFF_W1P);
    ushort_t* w2p = (ushort_t*)((char*)d_ws + OFF_W2P);

    hipMemsetAsync(d_ws, 0, 8, stream);
    stats_kernel<<<256, 256, 0, stream>>>(x, wsf);
    prep_bf16<<<512, 256, 0, stream>>>(w0, w1, w2, w0p, w1p, w2p);
    mask_kernel<<<16, 256, 0, stream>>>(wm, wsf);
    fused_mfma<<<2048, 512, 0, stream>>>(x, b0, b1, b2, wsf, w0p, w1p, w2p, out);
}

// Round 4
// 377.909 us; speedup vs baseline: 18.0240x; 1.2736x over previous
//
#include <hip/hip_runtime.h>
#include <hip/hip_bf16.h>
#include <math.h>

#define BATCH 2048
#define L 168
#define NTOT (BATCH*L)

typedef unsigned short ushort_t;
typedef unsigned int uint_t;
typedef __attribute__((ext_vector_type(8))) short bhalf8;
typedef __attribute__((ext_vector_type(4))) float f32x4;

// ---- ws layout ----
// float idx [0..1] sum,sumsq ; [16..2320) mask ; [2320..2832) bias0p
#define WS_MASK_F 16
#define WS_B0P_F 2320
#define OFF_W0P 12288                      // bytes; 7*512*32*2 = 229376
#define OFF_W1P (OFF_W0P + 7*512*32*2)     // 241664; 16*384*32*2 = 393216
#define OFF_W2P (OFF_W1P + 16*384*32*2)    // 634880; 12*256*32*2 = 196608

// ---- LDS layout (bytes) ----
// h0: [144][512] u16 swizzled (stride 1024B)  -> later h1 [144][384] u16 (stride 768B)
// fA: [144][32] u16 swizzled (stride 64B)     -> later mask 2304 f32 (9216B)
// xn: 168 f32
#define OFF_FA 147456
#define OFF_XN (OFF_FA + 9216)
#define LDS_TOTAL (OFF_XN + 672)

__device__ __forceinline__ ushort_t f2bf(float v) {
    union { float f; unsigned int u; } q; q.f = v;
    unsigned int u = q.u;
    u += 0x7FFFu + ((u >> 16) & 1u);
    return (ushort_t)(u >> 16);
}

__device__ __forceinline__ uint_t pack_bf16(float a, float b) {
    float2 t; t.x = a; t.y = b;
    __hip_bfloat162 h2 = __float22bfloat162_rn(t);
    uint_t u; __builtin_memcpy(&u, &h2, 4);
    return u;
}

__global__ __launch_bounds__(256) void stats_kernel(const float* __restrict__ x, float* ws) {
    __shared__ float s_sum[256], s_sq[256];
    int tid = threadIdx.x;
    int idx = blockIdx.x * 256 + tid;
    float sum = 0.f, sq = 0.f;
    const float4* x4 = (const float4*)x;
    for (int i = idx; i < NTOT / 4; i += gridDim.x * 256) {
        float4 v = x4[i];
        sum += v.x + v.y + v.z + v.w;
        sq  += v.x*v.x + v.y*v.y + v.z*v.z + v.w*v.w;
    }
    s_sum[tid] = sum; s_sq[tid] = sq;
    __syncthreads();
    for (int s = 128; s > 0; s >>= 1) {
        if (tid < s) { s_sum[tid] += s_sum[tid+s]; s_sq[tid] += s_sq[tid+s]; }
        __syncthreads();
    }
    if (tid == 0) { atomicAdd(&ws[0], s_sum[0]); atomicAdd(&ws[1], s_sq[0]); }
}

__global__ __launch_bounds__(256) void mask_kernel(const float* __restrict__ wm, float* __restrict__ ws) {
    __shared__ float sv[256];
    int g = blockIdx.x, t = threadIdx.x;
    float v = (t < 144) ? wm[g*144 + t] : -INFINITY;
    sv[t] = v;
    __syncthreads();
    for (int s = 128; s > 0; s >>= 1) { if (t < s) sv[t] = fmaxf(sv[t], sv[t+s]); __syncthreads(); }
    float mx = sv[0];
    __syncthreads();
    float e = (t < 144) ? expf(v - mx) : 0.f;
    sv[t] = e;
    __syncthreads();
    for (int s = 128; s > 0; s >>= 1) { if (t < s) sv[t] += sv[t+s]; __syncthreads(); }
    if (t < 144) ws[WS_MASK_F + g*144 + t] = e / sv[0];
}

// Transformed weight prep.
// L0 channels (K=224): ch<196: Wg = w0b + w0c/2 (pair ch) ; 196..209: Wq[n2]=sum_n1 w0a ;
// 210..223: Wp[n1] = -sum_n2 w0a. bias0p[o] = b0[o] + 0.5*sum_pr w0c.
__global__ __launch_bounds__(256) void prep_bf16(const float* __restrict__ w0, const float* __restrict__ b0,
                                                 const float* __restrict__ w1, const float* __restrict__ w2,
                                                 float* __restrict__ ws,
                                                 ushort_t* __restrict__ w0p, ushort_t* __restrict__ w1p,
                                                 ushort_t* __restrict__ w2p) {
    int idx = blockIdx.x * 256 + threadIdx.x;
    int stride = gridDim.x * 256;
    for (int i = idx; i < 7*16384; i += stride) {        // 512*32 per kt
        int kk = i & 31, o = (i >> 5) & 511, kt = i >> 14;
        int ch = kt*32 + kk;
        float v;
        if (ch < 196) {
            v = w0[o*588 + ch*3 + 1] + 0.5f * w0[o*588 + ch*3 + 2];
        } else if (ch < 210) {
            int n2 = ch - 196; float s = 0.f;
            for (int n1 = 0; n1 < 14; ++n1) s += w0[o*588 + (n1*14 + n2)*3];
            v = s;
        } else {
            int n1 = ch - 210; float s = 0.f;
            for (int n2 = 0; n2 < 14; ++n2) s += w0[o*588 + (n1*14 + n2)*3];
            v = -s;
        }
        w0p[i] = f2bf(v);
    }
    for (int i = idx; i < 16*12288; i += stride) {       // 384*32
        int kk = i & 31; int t = i >> 5; int o = t % 384; int kt = t / 384;
        w1p[i] = f2bf(w1[o*512 + kt*32 + kk]);
    }
    for (int i = idx; i < 12*8192; i += stride) {        // 256*32
        int kk = i & 31, o = (i >> 5) & 255, kt = i >> 13;
        w2p[i] = f2bf(w2[o*384 + kt*32 + kk]);
    }
    if (idx < 512) {
        float acc = 0.f;
        const float* wr = w0 + idx*588 + 2;
        for (int pr = 0; pr < 196; ++pr) acc += wr[3*pr];
        ws[WS_B0P_F + idx] = b0[idx] + 0.5f * acc;
    }
}

// One block per batch. 512 threads = 8 waves. M=144 (9 tiles).
__global__ __launch_bounds__(512, 2) void fused_mfma(
    const float* __restrict__ x,
    const float* __restrict__ b1, const float* __restrict__ b2,
    const float* __restrict__ wsf,
    const ushort_t* __restrict__ w0p, const ushort_t* __restrict__ w1p,
    const ushort_t* __restrict__ w2p, float* __restrict__ out)
{
    __shared__ __align__(16) char smem[LDS_TOTAL];
    float* xns = (float*)(smem + OFF_XN);

    const int tid  = threadIdx.x;
    const int b    = blockIdx.x;
    const int lane = tid & 63;
    const int w    = tid >> 6;
    const int col  = lane & 15;
    const int r4   = lane >> 4;
    const int swzA = (col & 7) << 4;     // row&7 == col&7 for rows m*16+col

    // ---- stats + xn ----
    {
        float sum = wsf[0], sq = wsf[1];
        float mean = sum / (float)NTOT;
        float var  = (sq - sum * mean) / (float)(NTOT - 1);
        float istd = 1.0f / sqrtf(var);
        if (tid < 168) xns[tid] = (x[b*L + tid] - mean) * istd;
    }
    __syncthreads();

    // ---- feature gen for K-tile kt into fA (32 ch, packed pairs) ----
    const int kk2 = tid & 15;
    const int rg  = tid >> 4;            // 0..31
    auto evalc = [&](int c, int h, int wv) -> float {
        if (c < 196) {
            int n1 = (c * 293) >> 12, n2 = c - 14*n1;
            float xi = xns[n1*12 + h], xj = xns[n2*12 + wv];
            return (xj - xi) * __builtin_amdgcn_rcpf(xi + xj + 1e-5f);
        } else if (c < 210) {
            return xns[(c - 196)*12 + wv];
        } else {
            return xns[(c - 210)*12 + h];
        }
    };
    auto gen = [&](int kt, bool mixed) {
        int c0 = kt*32 + kk2*2;
        int n1a = 0, n2a = 0, n1b = 0, n2b = 0;
        if (!mixed) {
            n1a = (c0 * 293) >> 12;       n2a = c0 - 14*n1a;
            n1b = ((c0+1) * 293) >> 12;   n2b = (c0+1) - 14*n1b;
        }
        #pragma unroll
        for (int j = 0; j < 5; ++j) {
            int r = rg + 32*j;
            if (r < 144) {
                int h  = (r * 171) >> 11;
                int wv = r - h*12;
                float v0, v1;
                if (!mixed) {
                    float xi0 = xns[n1a*12 + h], xj0 = xns[n2a*12 + wv];
                    v0 = (xj0 - xi0) * __builtin_amdgcn_rcpf(xi0 + xj0 + 1e-5f);
                    float xi1 = xns[n1b*12 + h], xj1 = xns[n2b*12 + wv];
                    v1 = (xj1 - xi1) * __builtin_amdgcn_rcpf(xi1 + xj1 + 1e-5f);
                } else {
                    v0 = evalc(c0, h, wv);
                    v1 = evalc(c0 + 1, h, wv);
                }
                *(uint_t*)(smem + OFF_FA + (((r << 6) + (kk2 << 2)) ^ ((r & 7) << 4))) = pack_bf16(v0, v1);
            }
        }
    };

    // ================= Layer 0: K=224 (7 kt) -> 512 =================
    {
        const int NT0 = w * 4;
        f32x4 acc[9][4];
        #pragma unroll
        for (int m = 0; m < 9; ++m)
            #pragma unroll
            for (int nt = 0; nt < 4; ++nt) acc[m][nt] = (f32x4){0.f,0.f,0.f,0.f};

        #pragma unroll
        for (int kt = 0; kt < 7; ++kt) {
            bhalf8 B[4];
            #pragma unroll
            for (int nt = 0; nt < 4; ++nt)
                B[nt] = *(const bhalf8*)(w0p + kt*16384 + ((NT0+nt)*16 + col)*32 + r4*8);
            gen(kt, kt == 6);
            __syncthreads();
            #pragma unroll
            for (int m = 0; m < 9; ++m) {
                int row = m*16 + col;
                bhalf8 a = *(const bhalf8*)(smem + OFF_FA + (((row << 6) + (r4 << 4)) ^ swzA));
                #pragma unroll
                for (int nt = 0; nt < 4; ++nt)
                    acc[m][nt] = __builtin_amdgcn_mfma_f32_16x16x32_bf16(a, B[nt], acc[m][nt], 0, 0, 0);
            }
            __syncthreads();
        }
        // epilogue: bias0p + relu -> bf16 -> h0 (swizzled, stride 512 u16)
        const float* bias0p = wsf + WS_B0P_F;
        float bb[4];
        #pragma unroll
        for (int nt = 0; nt < 4; ++nt) bb[nt] = bias0p[(NT0+nt)*16 + col];
        #pragma unroll
        for (int m = 0; m < 9; ++m)
            #pragma unroll
            for (int nt = 0; nt < 4; ++nt) {
                int o = (NT0+nt)*16 + col;
                #pragma unroll
                for (int qp = 0; qp < 2; ++qp) {
                    float v0 = fmaxf(acc[m][nt][2*qp]   + bb[nt], 0.f);
                    float v1 = fmaxf(acc[m][nt][2*qp+1] + bb[nt], 0.f);
                    uint_t pk = pack_bf16(v0, v1);
                    int row0 = m*16 + r4*4 + 2*qp;
                    *(ushort_t*)(smem + (((row0 << 10) + (o << 1)) ^ ((row0 & 7) << 4))) = (ushort_t)pk;
                    int row1 = row0 + 1;
                    *(ushort_t*)(smem + (((row1 << 10) + (o << 1)) ^ ((row1 & 7) << 4))) = (ushort_t)(pk >> 16);
                }
            }
    }
    __syncthreads();

    // ================= Layer 1: 512 -> 384 (16 kt, no barriers) =================
    {
        const int NT1 = w * 3;
        f32x4 acc1[9][3];
        #pragma unroll
        for (int m = 0; m < 9; ++m)
            #pragma unroll
            for (int nt = 0; nt < 3; ++nt) acc1[m][nt] = (f32x4){0.f,0.f,0.f,0.f};

        bhalf8 BA[3], BB[3];
        #define LOADB1(dst, ktv) { _Pragma("unroll") \
            for (int nt = 0; nt < 3; ++nt) \
                dst[nt] = *(const bhalf8*)(w1p + (ktv)*12288 + ((NT1+nt)*16+col)*32 + r4*8); }
        #define PHASE1(B, ktv) { _Pragma("unroll") \
            for (int m = 0; m < 9; ++m) { \
                int row = m*16 + col; \
                bhalf8 a = *(const bhalf8*)(smem + (((row << 10) + ((ktv) << 6) + (r4 << 4)) ^ swzA)); \
                _Pragma("unroll") \
                for (int nt = 0; nt < 3; ++nt) \
                    acc1[m][nt] = __builtin_amdgcn_mfma_f32_16x16x32_bf16(a, B[nt], acc1[m][nt], 0, 0, 0); } }

        LOADB1(BA, 0);
        for (int ktb = 0; ktb < 8; ++ktb) {
            int kt = 2*ktb;
            LOADB1(BB, kt+1);
            PHASE1(BA, kt);
            if (kt+2 < 16) LOADB1(BA, kt+2);
            PHASE1(BB, kt+1);
        }
        __syncthreads();   // all h0 reads done
        float bb[3];
        #pragma unroll
        for (int nt = 0; nt < 3; ++nt) bb[nt] = b1[(NT1+nt)*16 + col];
        #pragma unroll
        for (int m = 0; m < 9; ++m)
            #pragma unroll
            for (int nt = 0; nt < 3; ++nt) {
                int o = (NT1+nt)*16 + col;
                #pragma unroll
                for (int qp = 0; qp < 2; ++qp) {
                    float v0 = fmaxf(acc1[m][nt][2*qp]   + bb[nt], 0.f);
                    float v1 = fmaxf(acc1[m][nt][2*qp+1] + bb[nt], 0.f);
                    uint_t pk = pack_bf16(v0, v1);
                    int row0 = m*16 + r4*4 + 2*qp;
                    *(ushort_t*)(smem + (((row0*768) + (o << 1)) ^ ((row0 & 7) << 4))) = (ushort_t)pk;
                    int row1 = row0 + 1;
                    *(ushort_t*)(smem + (((row1*768) + (o << 1)) ^ ((row1 & 7) << 4))) = (ushort_t)(pk >> 16);
                }
            }
    }
    // stage mask into fA region (dead after L0)
    {
        float* maskS = (float*)(smem + OFF_FA);
        const float* maskG = wsf + WS_MASK_F;
        for (int i = tid; i < 2304; i += 512) maskS[i] = maskG[i];
    }
    __syncthreads();

    // ================= Layer 2: 384 -> 256 (12 kt) + pool =================
    {
        const int NT2 = w * 2;
        f32x4 acc[9][2];
        #pragma unroll
        for (int m = 0; m < 9; ++m)
            #pragma unroll
            for (int nt = 0; nt < 2; ++nt) acc[m][nt] = (f32x4){0.f,0.f,0.f,0.f};

        bhalf8 BA[2], BB[2];
        #define LOADB2(dst, ktv) { _Pragma("unroll") \
            for (int nt = 0; nt < 2; ++nt) \
                dst[nt] = *(const bhalf8*)(w2p + (ktv)*8192 + ((NT2+nt)*16+col)*32 + r4*8); }
        #define PHASE2(B, ktv) { _Pragma("unroll") \
            for (int m = 0; m < 9; ++m) { \
                int row = m*16 + col; \
                bhalf8 a = *(const bhalf8*)(smem + (((row*768) + ((ktv) << 6) + (r4 << 4)) ^ swzA)); \
                _Pragma("unroll") \
                for (int nt = 0; nt < 2; ++nt) \
                    acc[m][nt] = __builtin_amdgcn_mfma_f32_16x16x32_bf16(a, B[nt], acc[m][nt], 0, 0, 0); } }

        LOADB2(BA, 0);
        for (int ktb = 0; ktb < 6; ++ktb) {
            int kt = 2*ktb;
            LOADB2(BB, kt+1);
            PHASE2(BA, kt);
            if (kt+2 < 12) LOADB2(BA, kt+2);
            PHASE2(BB, kt+1);
        }
        const float* maskS = (const float*)(smem + OFF_FA);
        float bb[2];
        #pragma unroll
        for (int nt = 0; nt < 2; ++nt) bb[nt] = b2[(NT2+nt)*16 + col];
        float pooled[2] = {0.f, 0.f};
        #pragma unroll
        for (int nt = 0; nt < 2; ++nt) {
            int g = NT2 + nt;
            #pragma unroll
            for (int m = 0; m < 9; ++m)
                #pragma unroll
                for (int q = 0; q < 4; ++q) {
                    int p = m*16 + r4*4 + q;
                    float v = fmaxf(acc[m][nt][q] + bb[nt], 0.f);
                    pooled[nt] += maskS[g*144 + p] * v;
                }
        }
        #pragma unroll
        for (int nt = 0; nt < 2; ++nt) {
            pooled[nt] += __shfl_xor(pooled[nt], 16);
            pooled[nt] += __shfl_xor(pooled[nt], 32);
            if (r4 == 0) out[b*256 + (NT2+nt)*16 + col] = fmaxf(pooled[nt], 0.f);
        }
    }
}

extern "C" void kernel_launch(void* const* d_in, const int* in_sizes, int n_in,
                              void* d_out, int out_size, void* d_ws, size_t ws_size,
                              hipStream_t stream) {
    const float* x  = (const float*)d_in[0];
    const float* w0 = (const float*)d_in[1];
    const float* b0 = (const float*)d_in[2];
    const float* w1 = (const float*)d_in[3];
    const float* b1 = (const float*)d_in[4];
    const float* w2 = (const float*)d_in[5];
    const float* b2 = (const float*)d_in[6];
    const float* wm = (const float*)d_in[7];
    float* out = (float*)d_out;
    float* wsf = (float*)d_ws;
    ushort_t* w0p = (ushort_t*)((char*)d_ws + OFF_W0P);
    ushort_t* w1p = (ushort_t*)((char*)d_ws + OFF_W1P);
    ushort_t* w2p = (ushort_t*)((char*)d_ws + OFF_W2P);

    hipMemsetAsync(d_ws, 0, 8, stream);
    stats_kernel<<<256, 256, 0, stream>>>(x, wsf);
    prep_bf16<<<512, 256, 0, stream>>>(w0, b0, w1, w2, wsf, w0p, w1p, w2p);
    mask_kernel<<<16, 256, 0, stream>>>(wm, wsf);
    fused_mfma<<<2048, 512, 0, stream>>>(x, b1, b2, wsf, w0p, w1p, w2p, out);
}